// Round 1
// baseline (672.654 us; speedup 1.0000x reference)
//
#include <hip/hip_runtime.h>
#include <hip/hip_bf16.h>
#include <math.h>

// Segment-prefix max:
//   for segment i (rows [start_i, start_i + sizes_i)), out[i][:] =
//   max over rows [start_i, start_i + sizes_i - window + 1) of x.
// Shapes (fixed by setup_inputs): x = [2048*512, 128] fp32, sizes = [2048] int,
// window = 3. Memory-bound: ~535 MB read / launch -> ~85 us floor @ 6.3 TB/s.

#define BLOCK 256

__device__ __forceinline__ float4 fmax4(float4 a, float4 b) {
    return make_float4(fmaxf(a.x, b.x), fmaxf(a.y, b.y),
                       fmaxf(a.z, b.z), fmaxf(a.w, b.w));
}

__global__ __launch_bounds__(BLOCK)
void seg_prefix_max_kernel(const float* __restrict__ x,
                           const int* __restrict__ sizes,
                           const int* __restrict__ wptr,
                           float* __restrict__ out,
                           int n_seg, int D) {
    const int seg = blockIdx.x;
    const int tid = threadIdx.x;
    const int w   = *wptr;

    // ---- start_i = sum(sizes[0..seg)) : strided sum + LDS tree reduce ----
    __shared__ int red[BLOCK];
    int partial = 0;
    for (int j = tid; j < seg; j += BLOCK) partial += sizes[j];
    red[tid] = partial;
    __syncthreads();
    for (int s = BLOCK / 2; s > 0; s >>= 1) {
        if (tid < s) red[tid] += red[tid + s];
        __syncthreads();
    }
    const int start = red[0];                 // visible: last iter ended with sync
    const int L     = sizes[seg] - w + 1;     // rows to reduce (510 here)

    // ---- strided max over rows; 32 x float4 lanes cover D=128 ----
    const int nc4  = D >> 2;                  // float4s per row (32)
    const int col4 = tid & 31;
    const int rg   = tid >> 5;                // 0..7 row groups

    float4 acc = make_float4(-INFINITY, -INFINITY, -INFINITY, -INFINITY);

    if (col4 < nc4) {
        const float4* xrow = (const float4*)x + (size_t)start * nc4 + col4;
        #pragma unroll 4
        for (int r = rg; r < L; r += 8) {
            float4 v = xrow[(size_t)r * nc4];
            acc = fmax4(acc, v);
        }
    }

    // ---- reduce the 8 row-group partials via LDS ----
    __shared__ float4 part[8][32];
    if (col4 < nc4) part[rg][col4] = acc;
    __syncthreads();

    if (tid < nc4) {
        float4 a = part[0][tid];
        #pragma unroll
        for (int j = 1; j < 8; ++j) a = fmax4(a, part[j][tid]);
        ((float4*)out)[(size_t)seg * nc4 + tid] = a;
    }
}

extern "C" void kernel_launch(void* const* d_in, const int* in_sizes, int n_in,
                              void* d_out, int out_size, void* d_ws, size_t ws_size,
                              hipStream_t stream) {
    const float* x     = (const float*)d_in[0];
    const int*   sizes = (const int*)d_in[1];
    const int*   wptr  = (const int*)d_in[2];
    float*       out   = (float*)d_out;

    const int n_seg = in_sizes[1];            // 2048
    const int D     = out_size / n_seg;       // 128

    seg_prefix_max_kernel<<<n_seg, BLOCK, 0, stream>>>(x, sizes, wptr, out, n_seg, D);
}